// Round 2
// baseline (224.234 us; speedup 1.0000x reference)
//
#include <hip/hip_runtime.h>

#define BB 8
#define NN 4096
#define LL 4096
#define CC 256

typedef short bf16x8 __attribute__((ext_vector_type(8)));
typedef _Float16 f16x8 __attribute__((ext_vector_type(8)));
typedef __fp16 hf16x2 __attribute__((ext_vector_type(2)));  // cvt_pkrtz return type
typedef float f32x4 __attribute__((ext_vector_type(4)));

__device__ __forceinline__ short f2bf(float f) {
  union { float f; unsigned u; } v; v.f = f;
  unsigned r = v.u + 0x7fffu + ((v.u >> 16) & 1u);
  return (short)(r >> 16);
}
// 8 consecutive f32 -> bf16x8 MFMA fragment (two float4 loads)
__device__ __forceinline__ bf16x8 ld8(const float* __restrict__ fp) {
  float4 a = *(const float4*)fp;
  float4 b = *(const float4*)(fp + 4);
  bf16x8 r;
  r[0] = f2bf(a.x); r[1] = f2bf(a.y); r[2] = f2bf(a.z); r[3] = f2bf(a.w);
  r[4] = f2bf(b.x); r[5] = f2bf(b.y); r[6] = f2bf(b.z); r[7] = f2bf(b.w);
  return r;
}

// ---------------------------------------------------------------------------
// Kernel A: projections (f32 inputs).  Also zeroes Zbuf (used by kb1 atomics;
// stream order guarantees completion before kb1 starts).
//   blocks 0..511   : Kt[b][l][o] = (Wk@img + bk)[o][l] * log2(e)/sqrt(32) (bf16)
//                     Vt[b][l][o] = (Wv@img + bv)[o][l]                    (f16)
//   blocks 512..1023: Qb[b][n][o] = (graph@Wq^T + bq)[n][o]                (bf16)
// ---------------------------------------------------------------------------
__global__ __launch_bounds__(256) void ka_proj(
    const float* __restrict__ graph, const float* __restrict__ img,
    const float* __restrict__ Wq, const float* __restrict__ bq,
    const float* __restrict__ Wk, const float* __restrict__ bk,
    const float* __restrict__ Wv, const float* __restrict__ bv,
    short* __restrict__ Qb, short* __restrict__ Kt, _Float16* __restrict__ Vt,
    float* __restrict__ Zbuf)
{
  const int tid = threadIdx.x;
  const int w = tid >> 6, lane = tid & 63, lo = lane & 15, q = lane >> 4;
  const int bid = blockIdx.x;
  if (bid < 512) {
    const int b = bid >> 6;
    if (tid < 64) Zbuf[(size_t)b * LL + ((bid & 63) << 6) + tid] = 0.0f;
    const int lt = ((bid & 63) << 6) + (w << 4);
    f32x4 aK0 = {0,0,0,0}, aK1 = {0,0,0,0}, aV0 = {0,0,0,0}, aV1 = {0,0,0,0};
    const float* ib = img + (size_t)b * CC * LL + lt + lo;
    #pragma unroll
    for (int cs = 0; cs < 8; ++cs) {
      const int c0 = cs * 32 + q * 8;
      bf16x8 bi;
      #pragma unroll
      for (int j = 0; j < 8; ++j) bi[j] = f2bf(ib[(size_t)(c0 + j) * LL]);
      bf16x8 wk0 = ld8(Wk + lo * CC + c0);
      bf16x8 wk1 = ld8(Wk + (lo + 16) * CC + c0);
      bf16x8 wv0 = ld8(Wv + lo * CC + c0);
      bf16x8 wv1 = ld8(Wv + (lo + 16) * CC + c0);
      aK0 = __builtin_amdgcn_mfma_f32_16x16x32_bf16(wk0, bi, aK0, 0, 0, 0);
      aK1 = __builtin_amdgcn_mfma_f32_16x16x32_bf16(wk1, bi, aK1, 0, 0, 0);
      aV0 = __builtin_amdgcn_mfma_f32_16x16x32_bf16(wv0, bi, aV0, 0, 0, 0);
      aV1 = __builtin_amdgcn_mfma_f32_16x16x32_bf16(wv1, bi, aV1, 0, 0, 0);
    }
    // fold 1/sqrt(32) * log2(e) into K so softmax exp becomes a raw v_exp_f32
    const float kscale = 0.2550348663f;
    const size_t row = ((size_t)b * LL + lt + lo) * 32;
    short4 s0, s1;
    s0.x = f2bf((aK0[0] + bk[q * 4 + 0]) * kscale);
    s0.y = f2bf((aK0[1] + bk[q * 4 + 1]) * kscale);
    s0.z = f2bf((aK0[2] + bk[q * 4 + 2]) * kscale);
    s0.w = f2bf((aK0[3] + bk[q * 4 + 3]) * kscale);
    s1.x = f2bf((aK1[0] + bk[16 + q * 4 + 0]) * kscale);
    s1.y = f2bf((aK1[1] + bk[16 + q * 4 + 1]) * kscale);
    s1.z = f2bf((aK1[2] + bk[16 + q * 4 + 2]) * kscale);
    s1.w = f2bf((aK1[3] + bk[16 + q * 4 + 3]) * kscale);
    *(short4*)(Kt + row + q * 4) = s0;
    *(short4*)(Kt + row + 16 + q * 4) = s1;
    union { hf16x2 h[2]; uint2 u; } p0, p1;
    p0.h[0] = __builtin_amdgcn_cvt_pkrtz(aV0[0] + bv[q * 4 + 0], aV0[1] + bv[q * 4 + 1]);
    p0.h[1] = __builtin_amdgcn_cvt_pkrtz(aV0[2] + bv[q * 4 + 2], aV0[3] + bv[q * 4 + 3]);
    p1.h[0] = __builtin_amdgcn_cvt_pkrtz(aV1[0] + bv[16 + q * 4 + 0], aV1[1] + bv[16 + q * 4 + 1]);
    p1.h[1] = __builtin_amdgcn_cvt_pkrtz(aV1[2] + bv[16 + q * 4 + 2], aV1[3] + bv[16 + q * 4 + 3]);
    *(uint2*)(Vt + row + q * 4) = p0.u;
    *(uint2*)(Vt + row + 16 + q * 4) = p1.u;
  } else {
    const int t = bid - 512;
    const int b = t >> 6;
    const int nt = ((t & 63) << 6) + (w << 4);
    bf16x8 ag = ld8(graph + ((size_t)b * NN + nt + lo) * 32 + q * 8);
    bf16x8 w0 = ld8(Wq + lo * 32 + q * 8);
    bf16x8 w1 = ld8(Wq + (lo + 16) * 32 + q * 8);
    f32x4 z = {0,0,0,0};
    f32x4 a0 = __builtin_amdgcn_mfma_f32_16x16x32_bf16(ag, w0, z, 0, 0, 0);
    f32x4 a1 = __builtin_amdgcn_mfma_f32_16x16x32_bf16(ag, w1, z, 0, 0, 0);
    const float b0 = bq[lo], b1 = bq[lo + 16];
    #pragma unroll
    for (int r = 0; r < 4; ++r) {
      const size_t rowq = ((size_t)b * NN + nt + q * 4 + r) * 32;
      Qb[rowq + lo] = f2bf(a0[r] + b0);
      Qb[rowq + 16 + lo] = f2bf(a1[r] + b1);
    }
  }
}

// ---------------------------------------------------------------------------
// Kernel B1: partial softmax denominators.  Grid = 8b x 64 ltile x 4 nq =
// 2048 blocks x 4 waves (8 blocks/CU -> 32 waves/CU).  Wave w: 64 l x 256 n.
// Z[b][l] += sum_n exp2(S'[l][n]) via device-scope atomicAdd (Zbuf zeroed in ka).
// ---------------------------------------------------------------------------
__global__ __launch_bounds__(256) void kb1_z(
    const short* __restrict__ Qb, const short* __restrict__ Kt,
    float* __restrict__ Z)
{
  const int tid = threadIdx.x;
  const int w = tid >> 6, lane = tid & 63, lo = lane & 15, q = lane >> 4;
  const int bid = blockIdx.x;
  const int b = bid >> 8;
  const int l0 = ((bid >> 2) & 63) << 6;
  const int nq = bid & 3;
  bf16x8 kf[4];
  #pragma unroll
  for (int f = 0; f < 4; ++f)
    kf[f] = *(const bf16x8*)(Kt + ((size_t)b * LL + l0 + f * 16 + lo) * 32 + q * 8);
  float za[4][4] = {{0}};
  const short* qbase = Qb + ((size_t)b * NN + nq * 1024 + w * 256 + lo) * 32 + q * 8;
  #pragma unroll 4
  for (int it = 0; it < 16; ++it) {
    bf16x8 qf = *(const bf16x8*)(qbase + it * 512);
    #pragma unroll
    for (int f = 0; f < 4; ++f) {
      f32x4 z = {0,0,0,0};
      f32x4 c = __builtin_amdgcn_mfma_f32_16x16x32_bf16(kf[f], qf, z, 0, 0, 0);
      #pragma unroll
      for (int r = 0; r < 4; ++r) za[f][r] += __builtin_amdgcn_exp2f(c[r]);
    }
  }
  // reduce over n (= lo, low 4 lane bits)
  #pragma unroll
  for (int m = 1; m < 16; m <<= 1)
    #pragma unroll
    for (int f = 0; f < 4; ++f)
      #pragma unroll
      for (int r = 0; r < 4; ++r)
        za[f][r] += __shfl_xor(za[f][r], m, 64);
  if (lo == 0) {
    #pragma unroll
    for (int f = 0; f < 4; ++f)
      #pragma unroll
      for (int r = 0; r < 4; ++r)
        atomicAdd(&Z[(size_t)b * LL + l0 + f * 16 + q * 4 + r], za[f][r]);
  }
}

// ---------------------------------------------------------------------------
// Kernel B2: Vpp[b][o][l] = Vt[b][l][o] * (4096 / Z_l)  (f16, [o][l] layout).
// 512 blocks x 256 threads; thread: one l, 8 o's.
// ---------------------------------------------------------------------------
__global__ __launch_bounds__(256) void kb2_scale(
    const _Float16* __restrict__ Vt, const float* __restrict__ Z,
    _Float16* __restrict__ Vpp)
{
  const int tid = threadIdx.x;
  const int b = blockIdx.x >> 6;
  const int l = ((blockIdx.x & 63) << 6) + (tid & 63);
  const int og = tid >> 6;  // 0..3
  const float inv = __builtin_amdgcn_rcpf(Z[(size_t)b * LL + l]) * 4096.0f;
  const f16x8 vv = *(const f16x8*)(Vt + ((size_t)b * LL + l) * 32 + og * 8);
  #pragma unroll
  for (int j = 0; j < 8; ++j)
    Vpp[((size_t)b * 32 + og * 8 + j) * LL + l] = (_Float16)((float)vv[j] * inv);
}

// ---------------------------------------------------------------------------
// Kernel C: pass 2.  Block = (b, 32 n); 512 threads / 8 waves; wave w covers
// l in [w*512,(w+1)*512) -> 8 lc iterations.  4 blocks/CU x 8 waves = 32
// waves/CU (was 16) to hide the QK->exp2->LDS->PV serial chain latency.
// P(LDS) and msg-partial LDS share one 36.9 KB region (per-wave regions; msg
// written only after the wave's final P read).  Epilogue pre-reduces the 8
// msg regions into region 0, then applies Wc from L2 (no wcr[] reg array,
// keeps VGPR <= 64 for 8 waves/SIMD).
// ---------------------------------------------------------------------------
__global__ __launch_bounds__(512, 8) void kc_attn(
    const short* __restrict__ Qb, const short* __restrict__ Kt,
    const _Float16* __restrict__ Vpp, const float* __restrict__ graph,
    const float* __restrict__ Wc, const float* __restrict__ bc,
    float* __restrict__ out)
{
  __shared__ __align__(16) unsigned char smem[8 * 32 * 72 * 2];  // 36864 B
  const int tid = threadIdx.x;
  const int w = tid >> 6, lane = tid & 63, lo = lane & 15, q = lane >> 4;
  const int b = blockIdx.x >> 7;
  const int n0 = (blockIdx.x & 127) << 5;
  _Float16* Pw = (_Float16*)smem + w * (32 * 72);     // [32 n][72] per wave
  float* MS = (float*)smem;                           // [8][32][36] (post-loop)
  const bf16x8 qf0 = *(const bf16x8*)(Qb + ((size_t)b * NN + n0 + lo) * 32 + q * 8);
  const bf16x8 qf1 = *(const bf16x8*)(Qb + ((size_t)b * NN + n0 + 16 + lo) * 32 + q * 8);
  f32x4 m00 = {0,0,0,0}, m01 = {0,0,0,0}, m10 = {0,0,0,0}, m11 = {0,0,0,0};
  const short* ktb = Kt + (size_t)b * LL * 32 + lo * 32 + q * 8;
  const _Float16* vb0 = Vpp + ((size_t)b * 32 + lo) * LL;
  const _Float16* vb1 = vb0 + (size_t)16 * LL;
  const int lc0 = w * 8;
  bf16x8 kfN[4];
  #pragma unroll
  for (int f = 0; f < 4; ++f)
    kfN[f] = *(const bf16x8*)(ktb + (size_t)(lc0 * 64 + f * 16) * 32);
  for (int lc = lc0; lc < lc0 + 8; ++lc) {
    const int lbase = lc * 64;
    bf16x8 kfC[4];
    #pragma unroll
    for (int f = 0; f < 4; ++f) kfC[f] = kfN[f];
    // V frags for this lc (consumed ~200cy later in the k-loop)
    f16x8 vA0 = *(const f16x8*)(vb0 + lbase + q * 8);
    f16x8 vA1 = *(const f16x8*)(vb0 + lbase + 32 + q * 8);
    f16x8 vB0 = *(const f16x8*)(vb1 + lbase + q * 8);
    f16x8 vB1 = *(const f16x8*)(vb1 + lbase + 32 + q * 8);
    // prefetch next-lc Kt frags (clamped, branchless)
    const int lcn = (lc + 1 < lc0 + 8) ? lc + 1 : lc;
    #pragma unroll
    for (int f = 0; f < 4; ++f)
      kfN[f] = *(const bf16x8*)(ktb + (size_t)(lcn * 64 + f * 16) * 32);
    #pragma unroll
    for (int f = 0; f < 4; ++f) {
      f32x4 z = {0,0,0,0};
      f32x4 c0 = __builtin_amdgcn_mfma_f32_16x16x32_bf16(kfC[f], qf0, z, 0, 0, 0);
      f32x4 c1 = __builtin_amdgcn_mfma_f32_16x16x32_bf16(kfC[f], qf1, z, 0, 0, 0);
      union { hf16x2 h[2]; uint2 u; } pk0, pk1;
      pk0.h[0] = __builtin_amdgcn_cvt_pkrtz(__builtin_amdgcn_exp2f(c0[0]),
                                            __builtin_amdgcn_exp2f(c0[1]));
      pk0.h[1] = __builtin_amdgcn_cvt_pkrtz(__builtin_amdgcn_exp2f(c0[2]),
                                            __builtin_amdgcn_exp2f(c0[3]));
      pk1.h[0] = __builtin_amdgcn_cvt_pkrtz(__builtin_amdgcn_exp2f(c1[0]),
                                            __builtin_amdgcn_exp2f(c1[1]));
      pk1.h[1] = __builtin_amdgcn_cvt_pkrtz(__builtin_amdgcn_exp2f(c1[2]),
                                            __builtin_amdgcn_exp2f(c1[3]));
      *(uint2*)&Pw[lo * 72 + f * 16 + q * 4] = pk0.u;
      *(uint2*)&Pw[(16 + lo) * 72 + f * 16 + q * 4] = pk1.u;
    }
    {
      f16x8 pa00 = *(const f16x8*)&Pw[lo * 72 + q * 8];
      f16x8 pa01 = *(const f16x8*)&Pw[lo * 72 + 32 + q * 8];
      f16x8 pa10 = *(const f16x8*)&Pw[(16 + lo) * 72 + q * 8];
      f16x8 pa11 = *(const f16x8*)&Pw[(16 + lo) * 72 + 32 + q * 8];
      m00 = __builtin_amdgcn_mfma_f32_16x16x32_f16(pa00, vA0, m00, 0, 0, 0);
      m10 = __builtin_amdgcn_mfma_f32_16x16x32_f16(pa10, vA0, m10, 0, 0, 0);
      m01 = __builtin_amdgcn_mfma_f32_16x16x32_f16(pa00, vB0, m01, 0, 0, 0);
      m11 = __builtin_amdgcn_mfma_f32_16x16x32_f16(pa10, vB0, m11, 0, 0, 0);
      m00 = __builtin_amdgcn_mfma_f32_16x16x32_f16(pa01, vA1, m00, 0, 0, 0);
      m10 = __builtin_amdgcn_mfma_f32_16x16x32_f16(pa11, vA1, m10, 0, 0, 0);
      m01 = __builtin_amdgcn_mfma_f32_16x16x32_f16(pa01, vB1, m01, 0, 0, 0);
      m11 = __builtin_amdgcn_mfma_f32_16x16x32_f16(pa11, vB1, m11, 0, 0, 0);
    }
  }
  // stash msg partials into the SAME LDS region (all P reads for this wave done)
  float* MSw = MS + w * (32 * 36);
  #pragma unroll
  for (int r = 0; r < 4; ++r) {
    MSw[(q * 4 + r) * 36 + lo] = m00[r];
    MSw[(q * 4 + r) * 36 + 16 + lo] = m01[r];
    MSw[(16 + q * 4 + r) * 36 + lo] = m10[r];
    MSw[(16 + q * 4 + r) * 36 + 16 + lo] = m11[r];
  }
  __syncthreads();
  // pre-reduce the 8 per-wave msg regions into region 0 (288 threads x f32x4)
  if (tid < 288) {
    f32x4 s = *(const f32x4*)&MS[tid * 4];
    #pragma unroll
    for (int k = 1; k < 8; ++k) s += *(const f32x4*)&MS[k * 1152 + tid * 4];
    *(f32x4*)&MS[tid * 4] = s;
  }
  __syncthreads();
  // epilogue: out[n][o] = graph + bc[o] + sum_c Wc[o][c]*msg[n][c] / 4096
  const int o = lane & 31, nh = lane >> 5;
  const float bcv = bc[o];
  #pragma unroll
  for (int rr = 0; rr < 2; ++rr) {
    const int nl = w * 4 + nh * 2 + rr;
    f32x4 s = {0,0,0,0};
    #pragma unroll
    for (int cc = 0; cc < 8; ++cc) {
      f32x4 m4 = *(const f32x4*)&MS[nl * 36 + cc * 4];
      float4 wc4 = *(const float4*)(Wc + o * 32 + cc * 4);
      s[0] += wc4.x * m4[0];
      s[1] += wc4.y * m4[1];
      s[2] += wc4.z * m4[2];
      s[3] += wc4.w * m4[3];
    }
    const size_t idx = ((size_t)b * NN + n0 + nl) * 32 + o;
    out[idx] = (s[0] + s[1] + s[2] + s[3]) * (1.0f / 4096.0f) + bcv + graph[idx];
  }
}

// ---------------------------------------------------------------------------
extern "C" void kernel_launch(void* const* d_in, const int* in_sizes, int n_in,
                              void* d_out, int out_size, void* d_ws, size_t ws_size,
                              hipStream_t stream) {
  const float* graph = (const float*)d_in[0];
  const float* img   = (const float*)d_in[1];
  const float* Wq    = (const float*)d_in[2];
  const float* bq    = (const float*)d_in[3];
  const float* Wk    = (const float*)d_in[4];
  const float* bk    = (const float*)d_in[5];
  const float* Wv    = (const float*)d_in[6];
  const float* bv    = (const float*)d_in[7];
  const float* Wc    = (const float*)d_in[8];
  const float* bc    = (const float*)d_in[9];
  char* ws = (char*)d_ws;
  short*    Qb  = (short*)(ws + 0);          // 2 MB   bf16 [B][N][32]
  short*    Kt  = (short*)(ws + 2097152);    // 2 MB   bf16 [B][L][32] (scaled)
  _Float16* Vt  = (_Float16*)(ws + 4194304); // 2 MB   f16  [B][L][32]
  _Float16* Vpp = (_Float16*)(ws + 6291456); // 2 MB   f16  [B][32][L] (V*4096/Z)
  float*    Zb  = (float*)(ws + 8388608);    // 128 KB f32  [B][L]
  ka_proj<<<dim3(1024), dim3(256), 0, stream>>>(graph, img, Wq, bq, Wk, bk, Wv, bv,
                                                Qb, Kt, Vt, Zb);
  kb1_z<<<dim3(2048), dim3(256), 0, stream>>>(Qb, Kt, Zb);
  kb2_scale<<<dim3(512), dim3(256), 0, stream>>>(Vt, Zb, Vpp);
  kc_attn<<<dim3(1024), dim3(512), 0, stream>>>(Qb, Kt, Vpp, graph, Wc, bc,
                                                (float*)d_out);
}

// Round 3
// 206.987 us; speedup vs baseline: 1.0833x; 1.0833x over previous
//
#include <hip/hip_runtime.h>

#define BB 8
#define NN 4096
#define LL 4096
#define CC 256

typedef short bf16x8 __attribute__((ext_vector_type(8)));
typedef _Float16 f16x8 __attribute__((ext_vector_type(8)));
typedef __fp16 hf16x2 __attribute__((ext_vector_type(2)));  // cvt_pkrtz return type
typedef float f32x4 __attribute__((ext_vector_type(4)));

__device__ __forceinline__ short f2bf(float f) {
  union { float f; unsigned u; } v; v.f = f;
  unsigned r = v.u + 0x7fffu + ((v.u >> 16) & 1u);
  return (short)(r >> 16);
}
// 8 consecutive f32 -> bf16x8 MFMA fragment (two float4 loads)
__device__ __forceinline__ bf16x8 ld8(const float* __restrict__ fp) {
  float4 a = *(const float4*)fp;
  float4 b = *(const float4*)(fp + 4);
  bf16x8 r;
  r[0] = f2bf(a.x); r[1] = f2bf(a.y); r[2] = f2bf(a.z); r[3] = f2bf(a.w);
  r[4] = f2bf(b.x); r[5] = f2bf(b.y); r[6] = f2bf(b.z); r[7] = f2bf(b.w);
  return r;
}

// ---------------------------------------------------------------------------
// Kernel A: projections (f32 inputs).  Also zeroes Zbuf (used by kb1 atomics;
// stream order guarantees completion before kb1 starts).
//   blocks 0..511   : Kt[b][l][o] = (Wk@img + bk)[o][l] * log2(e)/sqrt(32) (bf16)
//                     Vt[b][l][o] = (Wv@img + bv)[o][l]                    (f16)
//   blocks 512..1023: Qb[b][n][o] = (graph@Wq^T + bq)[n][o]                (bf16)
// ---------------------------------------------------------------------------
__global__ __launch_bounds__(256) void ka_proj(
    const float* __restrict__ graph, const float* __restrict__ img,
    const float* __restrict__ Wq, const float* __restrict__ bq,
    const float* __restrict__ Wk, const float* __restrict__ bk,
    const float* __restrict__ Wv, const float* __restrict__ bv,
    short* __restrict__ Qb, short* __restrict__ Kt, _Float16* __restrict__ Vt,
    float* __restrict__ Zbuf)
{
  const int tid = threadIdx.x;
  const int w = tid >> 6, lane = tid & 63, lo = lane & 15, q = lane >> 4;
  const int bid = blockIdx.x;
  if (bid < 512) {
    const int b = bid >> 6;
    if (tid < 64) Zbuf[(size_t)b * LL + ((bid & 63) << 6) + tid] = 0.0f;
    const int lt = ((bid & 63) << 6) + (w << 4);
    f32x4 aK0 = {0,0,0,0}, aK1 = {0,0,0,0}, aV0 = {0,0,0,0}, aV1 = {0,0,0,0};
    const float* ib = img + (size_t)b * CC * LL + lt + lo;
    #pragma unroll
    for (int cs = 0; cs < 8; ++cs) {
      const int c0 = cs * 32 + q * 8;
      bf16x8 bi;
      #pragma unroll
      for (int j = 0; j < 8; ++j) bi[j] = f2bf(ib[(size_t)(c0 + j) * LL]);
      bf16x8 wk0 = ld8(Wk + lo * CC + c0);
      bf16x8 wk1 = ld8(Wk + (lo + 16) * CC + c0);
      bf16x8 wv0 = ld8(Wv + lo * CC + c0);
      bf16x8 wv1 = ld8(Wv + (lo + 16) * CC + c0);
      aK0 = __builtin_amdgcn_mfma_f32_16x16x32_bf16(wk0, bi, aK0, 0, 0, 0);
      aK1 = __builtin_amdgcn_mfma_f32_16x16x32_bf16(wk1, bi, aK1, 0, 0, 0);
      aV0 = __builtin_amdgcn_mfma_f32_16x16x32_bf16(wv0, bi, aV0, 0, 0, 0);
      aV1 = __builtin_amdgcn_mfma_f32_16x16x32_bf16(wv1, bi, aV1, 0, 0, 0);
    }
    // fold 1/sqrt(32) * log2(e) into K so softmax exp becomes a raw v_exp_f32
    const float kscale = 0.2550348663f;
    const size_t row = ((size_t)b * LL + lt + lo) * 32;
    short4 s0, s1;
    s0.x = f2bf((aK0[0] + bk[q * 4 + 0]) * kscale);
    s0.y = f2bf((aK0[1] + bk[q * 4 + 1]) * kscale);
    s0.z = f2bf((aK0[2] + bk[q * 4 + 2]) * kscale);
    s0.w = f2bf((aK0[3] + bk[q * 4 + 3]) * kscale);
    s1.x = f2bf((aK1[0] + bk[16 + q * 4 + 0]) * kscale);
    s1.y = f2bf((aK1[1] + bk[16 + q * 4 + 1]) * kscale);
    s1.z = f2bf((aK1[2] + bk[16 + q * 4 + 2]) * kscale);
    s1.w = f2bf((aK1[3] + bk[16 + q * 4 + 3]) * kscale);
    *(short4*)(Kt + row + q * 4) = s0;
    *(short4*)(Kt + row + 16 + q * 4) = s1;
    union { hf16x2 h[2]; uint2 u; } p0, p1;
    p0.h[0] = __builtin_amdgcn_cvt_pkrtz(aV0[0] + bv[q * 4 + 0], aV0[1] + bv[q * 4 + 1]);
    p0.h[1] = __builtin_amdgcn_cvt_pkrtz(aV0[2] + bv[q * 4 + 2], aV0[3] + bv[q * 4 + 3]);
    p1.h[0] = __builtin_amdgcn_cvt_pkrtz(aV1[0] + bv[16 + q * 4 + 0], aV1[1] + bv[16 + q * 4 + 1]);
    p1.h[1] = __builtin_amdgcn_cvt_pkrtz(aV1[2] + bv[16 + q * 4 + 2], aV1[3] + bv[16 + q * 4 + 3]);
    *(uint2*)(Vt + row + q * 4) = p0.u;
    *(uint2*)(Vt + row + 16 + q * 4) = p1.u;
  } else {
    const int t = bid - 512;
    const int b = t >> 6;
    const int nt = ((t & 63) << 6) + (w << 4);
    bf16x8 ag = ld8(graph + ((size_t)b * NN + nt + lo) * 32 + q * 8);
    bf16x8 w0 = ld8(Wq + lo * 32 + q * 8);
    bf16x8 w1 = ld8(Wq + (lo + 16) * 32 + q * 8);
    f32x4 z = {0,0,0,0};
    f32x4 a0 = __builtin_amdgcn_mfma_f32_16x16x32_bf16(ag, w0, z, 0, 0, 0);
    f32x4 a1 = __builtin_amdgcn_mfma_f32_16x16x32_bf16(ag, w1, z, 0, 0, 0);
    const float b0 = bq[lo], b1 = bq[lo + 16];
    #pragma unroll
    for (int r = 0; r < 4; ++r) {
      const size_t rowq = ((size_t)b * NN + nt + q * 4 + r) * 32;
      Qb[rowq + lo] = f2bf(a0[r] + b0);
      Qb[rowq + 16 + lo] = f2bf(a1[r] + b1);
    }
  }
}

// ---------------------------------------------------------------------------
// Kernel B1: partial softmax denominators.  Grid = 8b x 64 ltile x 4 nq =
// 2048 blocks x 4 waves (8 blocks/CU -> 32 waves/CU).  Wave w: 64 l x 256 n.
// Z[b][l] += sum_n exp2(S'[l][n]) via device-scope atomicAdd (Zbuf zeroed in ka).
// ---------------------------------------------------------------------------
__global__ __launch_bounds__(256) void kb1_z(
    const short* __restrict__ Qb, const short* __restrict__ Kt,
    float* __restrict__ Z)
{
  const int tid = threadIdx.x;
  const int w = tid >> 6, lane = tid & 63, lo = lane & 15, q = lane >> 4;
  const int bid = blockIdx.x;
  const int b = bid >> 8;
  const int l0 = ((bid >> 2) & 63) << 6;
  const int nq = bid & 3;
  bf16x8 kf[4];
  #pragma unroll
  for (int f = 0; f < 4; ++f)
    kf[f] = *(const bf16x8*)(Kt + ((size_t)b * LL + l0 + f * 16 + lo) * 32 + q * 8);
  float za[4][4] = {{0}};
  const short* qbase = Qb + ((size_t)b * NN + nq * 1024 + w * 256 + lo) * 32 + q * 8;
  #pragma unroll 4
  for (int it = 0; it < 16; ++it) {
    bf16x8 qf = *(const bf16x8*)(qbase + it * 512);
    #pragma unroll
    for (int f = 0; f < 4; ++f) {
      f32x4 z = {0,0,0,0};
      f32x4 c = __builtin_amdgcn_mfma_f32_16x16x32_bf16(kf[f], qf, z, 0, 0, 0);
      #pragma unroll
      for (int r = 0; r < 4; ++r) za[f][r] += __builtin_amdgcn_exp2f(c[r]);
    }
  }
  // reduce over n (= lo, low 4 lane bits)
  #pragma unroll
  for (int m = 1; m < 16; m <<= 1)
    #pragma unroll
    for (int f = 0; f < 4; ++f)
      #pragma unroll
      for (int r = 0; r < 4; ++r)
        za[f][r] += __shfl_xor(za[f][r], m, 64);
  if (lo == 0) {
    #pragma unroll
    for (int f = 0; f < 4; ++f)
      #pragma unroll
      for (int r = 0; r < 4; ++r)
        atomicAdd(&Z[(size_t)b * LL + l0 + f * 16 + q * 4 + r], za[f][r]);
  }
}

// ---------------------------------------------------------------------------
// Kernel B2: Vpp[b][o][l] = Vt[b][l][o] * (4096 / Z_l)  (f16, [o][l] layout).
// 512 blocks x 256 threads; thread: one l, 8 o's.
// ---------------------------------------------------------------------------
__global__ __launch_bounds__(256) void kb2_scale(
    const _Float16* __restrict__ Vt, const float* __restrict__ Z,
    _Float16* __restrict__ Vpp)
{
  const int tid = threadIdx.x;
  const int b = blockIdx.x >> 6;
  const int l = ((blockIdx.x & 63) << 6) + (tid & 63);
  const int og = tid >> 6;  // 0..3
  const float inv = __builtin_amdgcn_rcpf(Z[(size_t)b * LL + l]) * 4096.0f;
  const f16x8 vv = *(const f16x8*)(Vt + ((size_t)b * LL + l) * 32 + og * 8);
  #pragma unroll
  for (int j = 0; j < 8; ++j)
    Vpp[((size_t)b * 32 + og * 8 + j) * LL + l] = (_Float16)((float)vv[j] * inv);
}

// ---------------------------------------------------------------------------
// Kernel C: pass 2.  Block = (b, 32 n); 512 threads / 8 waves; wave w covers
// l in [w*512,(w+1)*512) -> 8 lc iterations.  4 blocks/CU x 8 waves = 32
// waves/CU to hide the QK->exp2->LDS->PV serial chain latency.
// __launch_bounds__(512, 4): 128-VGPR budget.  (512, 8) forced VGPR<=64 and
// spilled ~70 MB/dispatch to scratch (round 2 post-mortem) -- never again.
// P(LDS) and msg-partial LDS share one 36.9 KB region (per-wave regions; msg
// written only after the wave's final P read).  Epilogue pre-reduces the 8
// msg regions into region 0, then applies Wc from L2.
// ---------------------------------------------------------------------------
__global__ __launch_bounds__(512, 4) void kc_attn(
    const short* __restrict__ Qb, const short* __restrict__ Kt,
    const _Float16* __restrict__ Vpp, const float* __restrict__ graph,
    const float* __restrict__ Wc, const float* __restrict__ bc,
    float* __restrict__ out)
{
  __shared__ __align__(16) unsigned char smem[8 * 32 * 72 * 2];  // 36864 B
  const int tid = threadIdx.x;
  const int w = tid >> 6, lane = tid & 63, lo = lane & 15, q = lane >> 4;
  const int b = blockIdx.x >> 7;
  const int n0 = (blockIdx.x & 127) << 5;
  _Float16* Pw = (_Float16*)smem + w * (32 * 72);     // [32 n][72] per wave
  float* MS = (float*)smem;                           // [8][32][36] (post-loop)
  const bf16x8 qf0 = *(const bf16x8*)(Qb + ((size_t)b * NN + n0 + lo) * 32 + q * 8);
  const bf16x8 qf1 = *(const bf16x8*)(Qb + ((size_t)b * NN + n0 + 16 + lo) * 32 + q * 8);
  f32x4 m00 = {0,0,0,0}, m01 = {0,0,0,0}, m10 = {0,0,0,0}, m11 = {0,0,0,0};
  const short* ktb = Kt + (size_t)b * LL * 32 + lo * 32 + q * 8;
  const _Float16* vb0 = Vpp + ((size_t)b * 32 + lo) * LL;
  const _Float16* vb1 = vb0 + (size_t)16 * LL;
  const int lc0 = w * 8;
  bf16x8 kfN[4];
  #pragma unroll
  for (int f = 0; f < 4; ++f)
    kfN[f] = *(const bf16x8*)(ktb + (size_t)(lc0 * 64 + f * 16) * 32);
  for (int lc = lc0; lc < lc0 + 8; ++lc) {
    const int lbase = lc * 64;
    bf16x8 kfC[4];
    #pragma unroll
    for (int f = 0; f < 4; ++f) kfC[f] = kfN[f];
    // V frags for this lc (consumed ~200cy later in the k-loop)
    f16x8 vA0 = *(const f16x8*)(vb0 + lbase + q * 8);
    f16x8 vA1 = *(const f16x8*)(vb0 + lbase + 32 + q * 8);
    f16x8 vB0 = *(const f16x8*)(vb1 + lbase + q * 8);
    f16x8 vB1 = *(const f16x8*)(vb1 + lbase + 32 + q * 8);
    // prefetch next-lc Kt frags (clamped, branchless)
    const int lcn = (lc + 1 < lc0 + 8) ? lc + 1 : lc;
    #pragma unroll
    for (int f = 0; f < 4; ++f)
      kfN[f] = *(const bf16x8*)(ktb + (size_t)(lcn * 64 + f * 16) * 32);
    #pragma unroll
    for (int f = 0; f < 4; ++f) {
      f32x4 z = {0,0,0,0};
      f32x4 c0 = __builtin_amdgcn_mfma_f32_16x16x32_bf16(kfC[f], qf0, z, 0, 0, 0);
      f32x4 c1 = __builtin_amdgcn_mfma_f32_16x16x32_bf16(kfC[f], qf1, z, 0, 0, 0);
      union { hf16x2 h[2]; uint2 u; } pk0, pk1;
      pk0.h[0] = __builtin_amdgcn_cvt_pkrtz(__builtin_amdgcn_exp2f(c0[0]),
                                            __builtin_amdgcn_exp2f(c0[1]));
      pk0.h[1] = __builtin_amdgcn_cvt_pkrtz(__builtin_amdgcn_exp2f(c0[2]),
                                            __builtin_amdgcn_exp2f(c0[3]));
      pk1.h[0] = __builtin_amdgcn_cvt_pkrtz(__builtin_amdgcn_exp2f(c1[0]),
                                            __builtin_amdgcn_exp2f(c1[1]));
      pk1.h[1] = __builtin_amdgcn_cvt_pkrtz(__builtin_amdgcn_exp2f(c1[2]),
                                            __builtin_amdgcn_exp2f(c1[3]));
      *(uint2*)&Pw[lo * 72 + f * 16 + q * 4] = pk0.u;
      *(uint2*)&Pw[(16 + lo) * 72 + f * 16 + q * 4] = pk1.u;
    }
    {
      f16x8 pa00 = *(const f16x8*)&Pw[lo * 72 + q * 8];
      f16x8 pa01 = *(const f16x8*)&Pw[lo * 72 + 32 + q * 8];
      f16x8 pa10 = *(const f16x8*)&Pw[(16 + lo) * 72 + q * 8];
      f16x8 pa11 = *(const f16x8*)&Pw[(16 + lo) * 72 + 32 + q * 8];
      m00 = __builtin_amdgcn_mfma_f32_16x16x32_f16(pa00, vA0, m00, 0, 0, 0);
      m10 = __builtin_amdgcn_mfma_f32_16x16x32_f16(pa10, vA0, m10, 0, 0, 0);
      m01 = __builtin_amdgcn_mfma_f32_16x16x32_f16(pa00, vB0, m01, 0, 0, 0);
      m11 = __builtin_amdgcn_mfma_f32_16x16x32_f16(pa10, vB0, m11, 0, 0, 0);
      m00 = __builtin_amdgcn_mfma_f32_16x16x32_f16(pa01, vA1, m00, 0, 0, 0);
      m10 = __builtin_amdgcn_mfma_f32_16x16x32_f16(pa11, vA1, m10, 0, 0, 0);
      m01 = __builtin_amdgcn_mfma_f32_16x16x32_f16(pa01, vB1, m01, 0, 0, 0);
      m11 = __builtin_amdgcn_mfma_f32_16x16x32_f16(pa11, vB1, m11, 0, 0, 0);
    }
  }
  // stash msg partials into the SAME LDS region (all P reads for this wave done)
  float* MSw = MS + w * (32 * 36);
  #pragma unroll
  for (int r = 0; r < 4; ++r) {
    MSw[(q * 4 + r) * 36 + lo] = m00[r];
    MSw[(q * 4 + r) * 36 + 16 + lo] = m01[r];
    MSw[(16 + q * 4 + r) * 36 + lo] = m10[r];
    MSw[(16 + q * 4 + r) * 36 + 16 + lo] = m11[r];
  }
  __syncthreads();
  // pre-reduce the 8 per-wave msg regions into region 0 (288 threads x f32x4)
  if (tid < 288) {
    f32x4 s = *(const f32x4*)&MS[tid * 4];
    #pragma unroll
    for (int k = 1; k < 8; ++k) s += *(const f32x4*)&MS[k * 1152 + tid * 4];
    *(f32x4*)&MS[tid * 4] = s;
  }
  __syncthreads();
  // epilogue: out[n][o] = graph + bc[o] + sum_c Wc[o][c]*msg[n][c] / 4096
  const int o = lane & 31, nh = lane >> 5;
  const float bcv = bc[o];
  #pragma unroll
  for (int rr = 0; rr < 2; ++rr) {
    const int nl = w * 4 + nh * 2 + rr;
    f32x4 s = {0,0,0,0};
    #pragma unroll
    for (int cc = 0; cc < 8; ++cc) {
      f32x4 m4 = *(const f32x4*)&MS[nl * 36 + cc * 4];
      float4 wc4 = *(const float4*)(Wc + o * 32 + cc * 4);
      s[0] += wc4.x * m4[0];
      s[1] += wc4.y * m4[1];
      s[2] += wc4.z * m4[2];
      s[3] += wc4.w * m4[3];
    }
    const size_t idx = ((size_t)b * NN + n0 + nl) * 32 + o;
    out[idx] = (s[0] + s[1] + s[2] + s[3]) * (1.0f / 4096.0f) + bcv + graph[idx];
  }
}

// ---------------------------------------------------------------------------
extern "C" void kernel_launch(void* const* d_in, const int* in_sizes, int n_in,
                              void* d_out, int out_size, void* d_ws, size_t ws_size,
                              hipStream_t stream) {
  const float* graph = (const float*)d_in[0];
  const float* img   = (const float*)d_in[1];
  const float* Wq    = (const float*)d_in[2];
  const float* bq    = (const float*)d_in[3];
  const float* Wk    = (const float*)d_in[4];
  const float* bk    = (const float*)d_in[5];
  const float* Wv    = (const float*)d_in[6];
  const float* bv    = (const float*)d_in[7];
  const float* Wc    = (const float*)d_in[8];
  const float* bc    = (const float*)d_in[9];
  char* ws = (char*)d_ws;
  short*    Qb  = (short*)(ws + 0);          // 2 MB   bf16 [B][N][32]
  short*    Kt  = (short*)(ws + 2097152);    // 2 MB   bf16 [B][L][32] (scaled)
  _Float16* Vt  = (_Float16*)(ws + 4194304); // 2 MB   f16  [B][L][32]
  _Float16* Vpp = (_Float16*)(ws + 6291456); // 2 MB   f16  [B][32][L] (V*4096/Z)
  float*    Zb  = (float*)(ws + 8388608);    // 128 KB f32  [B][L]
  ka_proj<<<dim3(1024), dim3(256), 0, stream>>>(graph, img, Wq, bq, Wk, bk, Wv, bv,
                                                Qb, Kt, Vt, Zb);
  kb1_z<<<dim3(2048), dim3(256), 0, stream>>>(Qb, Kt, Zb);
  kb2_scale<<<dim3(512), dim3(256), 0, stream>>>(Vt, Zb, Vpp);
  kc_attn<<<dim3(1024), dim3(512), 0, stream>>>(Qb, Kt, Vpp, graph, Wc, bc,
                                                (float*)d_out);
}

// Round 4
// 183.419 us; speedup vs baseline: 1.2225x; 1.1285x over previous
//
#include <hip/hip_runtime.h>

#define BB 8
#define NN 4096
#define LL 4096
#define CC 256

typedef short bf16x8 __attribute__((ext_vector_type(8)));
typedef _Float16 f16x8 __attribute__((ext_vector_type(8)));
typedef __fp16 hf16x2 __attribute__((ext_vector_type(2)));  // cvt_pkrtz return type
typedef float f32x4 __attribute__((ext_vector_type(4)));

__device__ __forceinline__ short f2bf(float f) {
  union { float f; unsigned u; } v; v.f = f;
  unsigned r = v.u + 0x7fffu + ((v.u >> 16) & 1u);
  return (short)(r >> 16);
}
// 8 consecutive f32 -> bf16x8 MFMA fragment (two float4 loads)
__device__ __forceinline__ bf16x8 ld8(const float* __restrict__ fp) {
  float4 a = *(const float4*)fp;
  float4 b = *(const float4*)(fp + 4);
  bf16x8 r;
  r[0] = f2bf(a.x); r[1] = f2bf(a.y); r[2] = f2bf(a.z); r[3] = f2bf(a.w);
  r[4] = f2bf(b.x); r[5] = f2bf(b.y); r[6] = f2bf(b.z); r[7] = f2bf(b.w);
  return r;
}

// ---------------------------------------------------------------------------
// Kernel A: projections (f32 inputs).  Also zeroes Zbuf (used by kb1 atomics;
// stream order guarantees completion before kb1 starts).
//   blocks 0..511   : Kt[b][l][o] = (Wk@img + bk)[o][l] * log2(e)/sqrt(32) (bf16)
//                     Vt[b][l][o] = (Wv@img + bv)[o][l]                    (f16)
//   blocks 512..1023: Qb[b][n][o] = (graph@Wq^T + bq)[n][o]                (bf16)
// ---------------------------------------------------------------------------
__global__ __launch_bounds__(256) void ka_proj(
    const float* __restrict__ graph, const float* __restrict__ img,
    const float* __restrict__ Wq, const float* __restrict__ bq,
    const float* __restrict__ Wk, const float* __restrict__ bk,
    const float* __restrict__ Wv, const float* __restrict__ bv,
    short* __restrict__ Qb, short* __restrict__ Kt, _Float16* __restrict__ Vt,
    float* __restrict__ Zbuf)
{
  const int tid = threadIdx.x;
  const int w = tid >> 6, lane = tid & 63, lo = lane & 15, q = lane >> 4;
  const int bid = blockIdx.x;
  if (bid < 512) {
    const int b = bid >> 6;
    if (tid < 64) Zbuf[(size_t)b * LL + ((bid & 63) << 6) + tid] = 0.0f;
    const int lt = ((bid & 63) << 6) + (w << 4);
    f32x4 aK0 = {0,0,0,0}, aK1 = {0,0,0,0}, aV0 = {0,0,0,0}, aV1 = {0,0,0,0};
    const float* ib = img + (size_t)b * CC * LL + lt + lo;
    #pragma unroll
    for (int cs = 0; cs < 8; ++cs) {
      const int c0 = cs * 32 + q * 8;
      bf16x8 bi;
      #pragma unroll
      for (int j = 0; j < 8; ++j) bi[j] = f2bf(ib[(size_t)(c0 + j) * LL]);
      bf16x8 wk0 = ld8(Wk + lo * CC + c0);
      bf16x8 wk1 = ld8(Wk + (lo + 16) * CC + c0);
      bf16x8 wv0 = ld8(Wv + lo * CC + c0);
      bf16x8 wv1 = ld8(Wv + (lo + 16) * CC + c0);
      aK0 = __builtin_amdgcn_mfma_f32_16x16x32_bf16(wk0, bi, aK0, 0, 0, 0);
      aK1 = __builtin_amdgcn_mfma_f32_16x16x32_bf16(wk1, bi, aK1, 0, 0, 0);
      aV0 = __builtin_amdgcn_mfma_f32_16x16x32_bf16(wv0, bi, aV0, 0, 0, 0);
      aV1 = __builtin_amdgcn_mfma_f32_16x16x32_bf16(wv1, bi, aV1, 0, 0, 0);
    }
    // fold 1/sqrt(32) * log2(e) into K so softmax exp becomes a raw v_exp_f32
    const float kscale = 0.2550348663f;
    const size_t row = ((size_t)b * LL + lt + lo) * 32;
    short4 s0, s1;
    s0.x = f2bf((aK0[0] + bk[q * 4 + 0]) * kscale);
    s0.y = f2bf((aK0[1] + bk[q * 4 + 1]) * kscale);
    s0.z = f2bf((aK0[2] + bk[q * 4 + 2]) * kscale);
    s0.w = f2bf((aK0[3] + bk[q * 4 + 3]) * kscale);
    s1.x = f2bf((aK1[0] + bk[16 + q * 4 + 0]) * kscale);
    s1.y = f2bf((aK1[1] + bk[16 + q * 4 + 1]) * kscale);
    s1.z = f2bf((aK1[2] + bk[16 + q * 4 + 2]) * kscale);
    s1.w = f2bf((aK1[3] + bk[16 + q * 4 + 3]) * kscale);
    *(short4*)(Kt + row + q * 4) = s0;
    *(short4*)(Kt + row + 16 + q * 4) = s1;
    union { hf16x2 h[2]; uint2 u; } p0, p1;
    p0.h[0] = __builtin_amdgcn_cvt_pkrtz(aV0[0] + bv[q * 4 + 0], aV0[1] + bv[q * 4 + 1]);
    p0.h[1] = __builtin_amdgcn_cvt_pkrtz(aV0[2] + bv[q * 4 + 2], aV0[3] + bv[q * 4 + 3]);
    p1.h[0] = __builtin_amdgcn_cvt_pkrtz(aV1[0] + bv[16 + q * 4 + 0], aV1[1] + bv[16 + q * 4 + 1]);
    p1.h[1] = __builtin_amdgcn_cvt_pkrtz(aV1[2] + bv[16 + q * 4 + 2], aV1[3] + bv[16 + q * 4 + 3]);
    *(uint2*)(Vt + row + q * 4) = p0.u;
    *(uint2*)(Vt + row + 16 + q * 4) = p1.u;
  } else {
    const int t = bid - 512;
    const int b = t >> 6;
    const int nt = ((t & 63) << 6) + (w << 4);
    bf16x8 ag = ld8(graph + ((size_t)b * NN + nt + lo) * 32 + q * 8);
    bf16x8 w0 = ld8(Wq + lo * 32 + q * 8);
    bf16x8 w1 = ld8(Wq + (lo + 16) * 32 + q * 8);
    f32x4 z = {0,0,0,0};
    f32x4 a0 = __builtin_amdgcn_mfma_f32_16x16x32_bf16(ag, w0, z, 0, 0, 0);
    f32x4 a1 = __builtin_amdgcn_mfma_f32_16x16x32_bf16(ag, w1, z, 0, 0, 0);
    const float b0 = bq[lo], b1 = bq[lo + 16];
    #pragma unroll
    for (int r = 0; r < 4; ++r) {
      const size_t rowq = ((size_t)b * NN + nt + q * 4 + r) * 32;
      Qb[rowq + lo] = f2bf(a0[r] + b0);
      Qb[rowq + 16 + lo] = f2bf(a1[r] + b1);
    }
  }
}

// ---------------------------------------------------------------------------
// Kernel B1: partial softmax denominators.  Grid = 8b x 64 ltile x 4 nq =
// 2048 blocks x 4 waves (8 blocks/CU -> 32 waves/CU).  Wave w: 64 l x 256 n.
// Z[b][l] += sum_n exp2(S'[l][n]) via device-scope atomicAdd (Zbuf zeroed in ka).
// ---------------------------------------------------------------------------
__global__ __launch_bounds__(256) void kb1_z(
    const short* __restrict__ Qb, const short* __restrict__ Kt,
    float* __restrict__ Z)
{
  const int tid = threadIdx.x;
  const int w = tid >> 6, lane = tid & 63, lo = lane & 15, q = lane >> 4;
  const int bid = blockIdx.x;
  const int b = bid >> 8;
  const int l0 = ((bid >> 2) & 63) << 6;
  const int nq = bid & 3;
  bf16x8 kf[4];
  #pragma unroll
  for (int f = 0; f < 4; ++f)
    kf[f] = *(const bf16x8*)(Kt + ((size_t)b * LL + l0 + f * 16 + lo) * 32 + q * 8);
  float za[4][4] = {{0}};
  const short* qbase = Qb + ((size_t)b * NN + nq * 1024 + w * 256 + lo) * 32 + q * 8;
  #pragma unroll 4
  for (int it = 0; it < 16; ++it) {
    bf16x8 qf = *(const bf16x8*)(qbase + it * 512);
    #pragma unroll
    for (int f = 0; f < 4; ++f) {
      f32x4 z = {0,0,0,0};
      f32x4 c = __builtin_amdgcn_mfma_f32_16x16x32_bf16(kf[f], qf, z, 0, 0, 0);
      #pragma unroll
      for (int r = 0; r < 4; ++r) za[f][r] += __builtin_amdgcn_exp2f(c[r]);
    }
  }
  // reduce over n (= lo, low 4 lane bits)
  #pragma unroll
  for (int m = 1; m < 16; m <<= 1)
    #pragma unroll
    for (int f = 0; f < 4; ++f)
      #pragma unroll
      for (int r = 0; r < 4; ++r)
        za[f][r] += __shfl_xor(za[f][r], m, 64);
  if (lo == 0) {
    #pragma unroll
    for (int f = 0; f < 4; ++f)
      #pragma unroll
      for (int r = 0; r < 4; ++r)
        atomicAdd(&Z[(size_t)b * LL + l0 + f * 16 + q * 4 + r], za[f][r]);
  }
}

// ---------------------------------------------------------------------------
// Kernel B2: Vpp[b][o][l] = Vt[b][l][o] * (4096 / Z_l)  (f16, [o][l] layout).
// 512 blocks x 256 threads; thread: one l, 8 o's.
// ---------------------------------------------------------------------------
__global__ __launch_bounds__(256) void kb2_scale(
    const _Float16* __restrict__ Vt, const float* __restrict__ Z,
    _Float16* __restrict__ Vpp)
{
  const int tid = threadIdx.x;
  const int b = blockIdx.x >> 6;
  const int l = ((blockIdx.x & 63) << 6) + (tid & 63);
  const int og = tid >> 6;  // 0..3
  const float inv = __builtin_amdgcn_rcpf(Z[(size_t)b * LL + l]) * 4096.0f;
  const f16x8 vv = *(const f16x8*)(Vt + ((size_t)b * LL + l) * 32 + og * 8);
  #pragma unroll
  for (int j = 0; j < 8; ++j)
    Vpp[((size_t)b * 32 + og * 8 + j) * LL + l] = (_Float16)((float)vv[j] * inv);
}

// ---------------------------------------------------------------------------
// Kernel C: pass 2.  r1 geometry (256 thr / 4 waves / 16 lc / 1024 blocks)
// with a lag-1 software pipeline: P double-buffered per wave in LDS; body i
// does QK(lc)+exp2+pack+write P[cur], then PV of P(lc-1) from P[prev] with
// V(lc-1) held in registers (loaded one body earlier).  Every LDS/global
// consumer sits >= 1 body (~400cy) behind its producer -> the per-iteration
// serial chain (~550cy in r1, measured 2170cy/slot at 4 waves/SIMD) collapses
// to ~max(VALU,MFMA) throughput.  Per-wave buffers -> barrier-free main loop.
// Msg partials land in each wave's own PA buffer (no cross-wave alias).
// __launch_bounds__(256,4) = 128-VGPR budget (r2 lesson: never cap below need).
// ---------------------------------------------------------------------------
#define KC_BODY(LC, PWR, PRD, DOPV)                                           \
  {                                                                           \
    const int lbase_ = (LC) * 64;                                             \
    const int lcn_ = ((LC) + 1 < lc0 + 16) ? (LC) + 1 : (LC);                 \
    bf16x8 kfN_[4];                                                           \
    _Pragma("unroll")                                                         \
    for (int f = 0; f < 4; ++f)                                               \
      kfN_[f] = *(const bf16x8*)(ktb + (size_t)(lcn_ * 64 + f * 16) * 32);    \
    f16x8 vN0_ = *(const f16x8*)(vb0 + lbase_ + q * 8);                       \
    f16x8 vN1_ = *(const f16x8*)(vb0 + lbase_ + 32 + q * 8);                  \
    f16x8 vN2_ = *(const f16x8*)(vb1 + lbase_ + q * 8);                       \
    f16x8 vN3_ = *(const f16x8*)(vb1 + lbase_ + 32 + q * 8);                  \
    _Pragma("unroll")                                                         \
    for (int f = 0; f < 4; ++f) {                                             \
      f32x4 z_ = {0, 0, 0, 0};                                                \
      f32x4 c0_ = __builtin_amdgcn_mfma_f32_16x16x32_bf16(kfC[f], qf0, z_, 0, 0, 0); \
      f32x4 c1_ = __builtin_amdgcn_mfma_f32_16x16x32_bf16(kfC[f], qf1, z_, 0, 0, 0); \
      union { hf16x2 h[2]; uint2 u; } pk0_, pk1_;                             \
      pk0_.h[0] = __builtin_amdgcn_cvt_pkrtz(__builtin_amdgcn_exp2f(c0_[0]),  \
                                             __builtin_amdgcn_exp2f(c0_[1])); \
      pk0_.h[1] = __builtin_amdgcn_cvt_pkrtz(__builtin_amdgcn_exp2f(c0_[2]),  \
                                             __builtin_amdgcn_exp2f(c0_[3])); \
      pk1_.h[0] = __builtin_amdgcn_cvt_pkrtz(__builtin_amdgcn_exp2f(c1_[0]),  \
                                             __builtin_amdgcn_exp2f(c1_[1])); \
      pk1_.h[1] = __builtin_amdgcn_cvt_pkrtz(__builtin_amdgcn_exp2f(c1_[2]),  \
                                             __builtin_amdgcn_exp2f(c1_[3])); \
      *(uint2*)&(PWR)[lo * 72 + f * 16 + q * 4] = pk0_.u;                     \
      *(uint2*)&(PWR)[(16 + lo) * 72 + f * 16 + q * 4] = pk1_.u;              \
    }                                                                         \
    if (DOPV) {                                                               \
      f16x8 pa00_ = *(const f16x8*)&(PRD)[lo * 72 + q * 8];                   \
      f16x8 pa01_ = *(const f16x8*)&(PRD)[lo * 72 + 32 + q * 8];              \
      f16x8 pa10_ = *(const f16x8*)&(PRD)[(16 + lo) * 72 + q * 8];            \
      f16x8 pa11_ = *(const f16x8*)&(PRD)[(16 + lo) * 72 + 32 + q * 8];       \
      m00 = __builtin_amdgcn_mfma_f32_16x16x32_f16(pa00_, vC0, m00, 0, 0, 0); \
      m10 = __builtin_amdgcn_mfma_f32_16x16x32_f16(pa10_, vC0, m10, 0, 0, 0); \
      m01 = __builtin_amdgcn_mfma_f32_16x16x32_f16(pa00_, vC2, m01, 0, 0, 0); \
      m11 = __builtin_amdgcn_mfma_f32_16x16x32_f16(pa10_, vC2, m11, 0, 0, 0); \
      m00 = __builtin_amdgcn_mfma_f32_16x16x32_f16(pa01_, vC1, m00, 0, 0, 0); \
      m10 = __builtin_amdgcn_mfma_f32_16x16x32_f16(pa11_, vC1, m10, 0, 0, 0); \
      m01 = __builtin_amdgcn_mfma_f32_16x16x32_f16(pa01_, vC3, m01, 0, 0, 0); \
      m11 = __builtin_amdgcn_mfma_f32_16x16x32_f16(pa11_, vC3, m11, 0, 0, 0); \
    }                                                                         \
    vC0 = vN0_; vC1 = vN1_; vC2 = vN2_; vC3 = vN3_;                           \
    _Pragma("unroll")                                                         \
    for (int f = 0; f < 4; ++f) kfC[f] = kfN_[f];                             \
  }

__global__ __launch_bounds__(256, 4) void kc_attn(
    const short* __restrict__ Qb, const short* __restrict__ Kt,
    const _Float16* __restrict__ Vpp, const float* __restrict__ graph,
    const float* __restrict__ Wc, const float* __restrict__ bc,
    float* __restrict__ out)
{
  __shared__ __align__(16) unsigned char smem[4 * 2 * 32 * 72 * 2];  // 36864 B
  const int tid = threadIdx.x;
  const int w = tid >> 6, lane = tid & 63, lo = lane & 15, q = lane >> 4;
  const int b = blockIdx.x >> 7;
  const int n0 = (blockIdx.x & 127) << 5;
  _Float16* PA = (_Float16*)smem + (w * 2 + 0) * (32 * 72);  // ping
  _Float16* PB = (_Float16*)smem + (w * 2 + 1) * (32 * 72);  // pong
  float* MS = (float*)smem;  // [4 waves][stride 2304 f32 = own PA buf][32][36]
  const bf16x8 qf0 = *(const bf16x8*)(Qb + ((size_t)b * NN + n0 + lo) * 32 + q * 8);
  const bf16x8 qf1 = *(const bf16x8*)(Qb + ((size_t)b * NN + n0 + 16 + lo) * 32 + q * 8);
  f32x4 m00 = {0,0,0,0}, m01 = {0,0,0,0}, m10 = {0,0,0,0}, m11 = {0,0,0,0};
  const short* ktb = Kt + (size_t)b * LL * 32 + lo * 32 + q * 8;
  const _Float16* vb0 = Vpp + ((size_t)b * 32 + lo) * LL;
  const _Float16* vb1 = vb0 + (size_t)16 * LL;
  const int lc0 = w * 16;
  bf16x8 kfC[4];
  #pragma unroll
  for (int f = 0; f < 4; ++f)
    kfC[f] = *(const bf16x8*)(ktb + (size_t)(lc0 * 64 + f * 16) * 32);
  f16x8 vC0 = {0,0,0,0,0,0,0,0}, vC1 = {0,0,0,0,0,0,0,0};
  f16x8 vC2 = {0,0,0,0,0,0,0,0}, vC3 = {0,0,0,0,0,0,0,0};
  #pragma unroll 1
  for (int i2 = 0; i2 < 8; ++i2) {
    const int lce = lc0 + i2 * 2;
    KC_BODY(lce, PA, PB, (i2 != 0));   // even: write PA, PV of prev odd (PB)
    KC_BODY(lce + 1, PB, PA, true);    // odd:  write PB, PV of even (PA)
  }
  // drain: PV of the last body's P (in PB), V(lc0+15) in vC
  {
    f16x8 pa00_ = *(const f16x8*)&PB[lo * 72 + q * 8];
    f16x8 pa01_ = *(const f16x8*)&PB[lo * 72 + 32 + q * 8];
    f16x8 pa10_ = *(const f16x8*)&PB[(16 + lo) * 72 + q * 8];
    f16x8 pa11_ = *(const f16x8*)&PB[(16 + lo) * 72 + 32 + q * 8];
    m00 = __builtin_amdgcn_mfma_f32_16x16x32_f16(pa00_, vC0, m00, 0, 0, 0);
    m10 = __builtin_amdgcn_mfma_f32_16x16x32_f16(pa10_, vC0, m10, 0, 0, 0);
    m01 = __builtin_amdgcn_mfma_f32_16x16x32_f16(pa00_, vC2, m01, 0, 0, 0);
    m11 = __builtin_amdgcn_mfma_f32_16x16x32_f16(pa10_, vC2, m11, 0, 0, 0);
    m00 = __builtin_amdgcn_mfma_f32_16x16x32_f16(pa01_, vC1, m00, 0, 0, 0);
    m10 = __builtin_amdgcn_mfma_f32_16x16x32_f16(pa11_, vC1, m10, 0, 0, 0);
    m01 = __builtin_amdgcn_mfma_f32_16x16x32_f16(pa01_, vC3, m01, 0, 0, 0);
    m11 = __builtin_amdgcn_mfma_f32_16x16x32_f16(pa11_, vC3, m11, 0, 0, 0);
  }
  // stash msg partials into this wave's OWN PA buffer (stride 2304 f32/wave)
  float* MSw = MS + w * 2304;
  #pragma unroll
  for (int r = 0; r < 4; ++r) {
    MSw[(q * 4 + r) * 36 + lo] = m00[r];
    MSw[(q * 4 + r) * 36 + 16 + lo] = m01[r];
    MSw[(16 + q * 4 + r) * 36 + lo] = m10[r];
    MSw[(16 + q * 4 + r) * 36 + 16 + lo] = m11[r];
  }
  __syncthreads();
  // epilogue: out[n][o] = graph + bc[o] + sum_c Wc[o][c]*msg[n][c] / 4096
  const int o = lane & 31, nh = lane >> 5;
  float wcr[32];
  #pragma unroll
  for (int c4 = 0; c4 < 8; ++c4) {
    float4 wc4 = *(const float4*)(Wc + o * 32 + c4 * 4);
    wcr[c4 * 4 + 0] = wc4.x * (1.0f / 4096.0f);
    wcr[c4 * 4 + 1] = wc4.y * (1.0f / 4096.0f);
    wcr[c4 * 4 + 2] = wc4.z * (1.0f / 4096.0f);
    wcr[c4 * 4 + 3] = wc4.w * (1.0f / 4096.0f);
  }
  const float bcv = bc[o];
  #pragma unroll
  for (int rr = 0; rr < 4; ++rr) {
    const int nl = w * 8 + nh * 4 + rr;
    f32x4 s = {0,0,0,0};
    #pragma unroll
    for (int cc = 0; cc < 8; ++cc) {
      f32x4 ma = *(const f32x4*)&MS[0 * 2304 + nl * 36 + cc * 4];
      f32x4 mb = *(const f32x4*)&MS[1 * 2304 + nl * 36 + cc * 4];
      f32x4 mc = *(const f32x4*)&MS[2 * 2304 + nl * 36 + cc * 4];
      f32x4 md = *(const f32x4*)&MS[3 * 2304 + nl * 36 + cc * 4];
      f32x4 m4 = ma + mb + mc + md;
      s[0] += wcr[cc * 4 + 0] * m4[0];
      s[1] += wcr[cc * 4 + 1] * m4[1];
      s[2] += wcr[cc * 4 + 2] * m4[2];
      s[3] += wcr[cc * 4 + 3] * m4[3];
    }
    const size_t idx = ((size_t)b * NN + n0 + nl) * 32 + o;
    out[idx] = s[0] + s[1] + s[2] + s[3] + bcv + graph[idx];
  }
}

// ---------------------------------------------------------------------------
extern "C" void kernel_launch(void* const* d_in, const int* in_sizes, int n_in,
                              void* d_out, int out_size, void* d_ws, size_t ws_size,
                              hipStream_t stream) {
  const float* graph = (const float*)d_in[0];
  const float* img   = (const float*)d_in[1];
  const float* Wq    = (const float*)d_in[2];
  const float* bq    = (const float*)d_in[3];
  const float* Wk    = (const float*)d_in[4];
  const float* bk    = (const float*)d_in[5];
  const float* Wv    = (const float*)d_in[6];
  const float* bv    = (const float*)d_in[7];
  const float* Wc    = (const float*)d_in[8];
  const float* bc    = (const float*)d_in[9];
  char* ws = (char*)d_ws;
  short*    Qb  = (short*)(ws + 0);          // 2 MB   bf16 [B][N][32]
  short*    Kt  = (short*)(ws + 2097152);    // 2 MB   bf16 [B][L][32] (scaled)
  _Float16* Vt  = (_Float16*)(ws + 4194304); // 2 MB   f16  [B][L][32]
  _Float16* Vpp = (_Float16*)(ws + 6291456); // 2 MB   f16  [B][32][L] (V*4096/Z)
  float*    Zb  = (float*)(ws + 8388608);    // 128 KB f32  [B][L]
  ka_proj<<<dim3(1024), dim3(256), 0, stream>>>(graph, img, Wq, bq, Wk, bk, Wv, bv,
                                                Qb, Kt, Vt, Zb);
  kb1_z<<<dim3(2048), dim3(256), 0, stream>>>(Qb, Kt, Zb);
  kb2_scale<<<dim3(512), dim3(256), 0, stream>>>(Vt, Zb, Vpp);
  kc_attn<<<dim3(1024), dim3(256), 0, stream>>>(Qb, Kt, Vpp, graph, Wc, bc,
                                                (float*)d_out);
}